// Round 5
// baseline (230.033 us; speedup 1.0000x reference)
//
#include <hip/hip_runtime.h>

#define L_LEN   16384
#define P_DIM   512
#define CHUNK   64
#define NCHUNK  256        // L_LEN / CHUNK
#define NBT     8          // blocks doing the Bt pack

#define KDIM    1024       // 2*P, interleaved: k=2c -> re(ch c), k=2c+1 -> im(ch c)
#define NDIM    512
#define BM      128
#define BN      256
#define BK      64

typedef __bf16 bf16_t;
typedef __bf16 bf16x8 __attribute__((ext_vector_type(8)));
typedef float  floatx4 __attribute__((ext_vector_type(4)));

// ONE kernel: Bt pack (blocks 0..7) + full scan with decoupled carry
// (blocks 8..263 = chunk c). carry = sum_j A_c^(c-1-j) * agg_j, terms
// independent; aggs read with PLAIN pipelined loads (8-wide batches) after a
// single acquire fence -- round-4's serial atomic loads were ~1000cy each.
__global__ void __launch_bounds__(512) k_scan_fused(
        const float* __restrict__ u, const float* __restrict__ Lam,
        const float* __restrict__ lstep, const float* __restrict__ Vre,
        const float* __restrict__ Vim, unsigned int* __restrict__ flags,
        unsigned long long* __restrict__ agg, bf16_t* __restrict__ Bt,
        bf16_t* __restrict__ A) {
    const int b   = blockIdx.x;
    const int tid = threadIdx.x;

    if (b < NBT) {   // ---- Bt pack: Bt[j][2c]=Vre[j][c], Bt[j][2c+1]=-Vim[j][c]
        const int base = b * (NDIM * P_DIM / NBT);
        #pragma unroll 4
        for (int i = 0; i < NDIM * P_DIM / NBT / 512; ++i) {
            int idx = base + i * 512 + tid;
            int j = idx >> 9;
            int c = idx & 511;
            union { unsigned int w; bf16_t h[2]; } pk;
            pk.h[0] = (bf16_t)Vre[j * P_DIM + c];
            pk.h[1] = (bf16_t)(-Vim[j * P_DIM + c]);
            ((unsigned int*)Bt)[idx] = pk.w;
        }
        return;
    }

    const int c = b - NBT;
    const int p = tid;

    // per-channel constants
    float lr = -expf(Lam[2 * p + 0]);
    float li = Lam[2 * p + 1];
    float s  = expf(lstep[p]);
    float er = expf(lr * s);
    float ar = er * cosf(li * s);
    float ai = er * sinf(li * s);
    float dr = ar - 1.0f, di = ai;
    float inv = 1.0f / (lr * lr + li * li);
    float br = (dr * lr + di * li) * inv;
    float bi = (di * lr - dr * li) * inv;
    // chunk-combine factor A_c = a^CHUNK (closed form)
    float tt = s * (float)CHUNK;
    float eR = expf(lr * tt);
    float Ar = eR * cosf(li * tt);
    float Ai = eR * sinf(li * tt);

    // pass A: local scan from zero, cache u in registers
    float uv[CHUNK];
    const float* up = u + (size_t)c * CHUNK * P_DIM + p;
    float xr = 0.f, xi = 0.f;
    #pragma unroll
    for (int t = 0; t < CHUNK; ++t) {
        uv[t] = up[(size_t)t * P_DIM];
        float nr = ar * xr - ai * xi + br * uv[t];
        float ni = ar * xi + ai * xr + bi * uv[t];
        xr = nr; xi = ni;
    }

    // publish aggregate (agent scope), then release flag
    union { unsigned long long ull; float f[2]; } pk;
    pk.f[0] = xr; pk.f[1] = xi;
    __hip_atomic_store(&agg[(size_t)c * P_DIM + p], pk.ull,
                       __ATOMIC_RELAXED, __HIP_MEMORY_SCOPE_AGENT);
    __threadfence();
    __syncthreads();
    if (tid == 0)
        __hip_atomic_store(&flags[c], 1u, __ATOMIC_RELEASE,
                           __HIP_MEMORY_SCOPE_AGENT);

    // lookback: wait for all predecessors, fence once, then pipelined reads
    float cr = 0.f, ci = 0.f;
    if (c > 0) {
        int ok;
        do {
            int f = 1;
            if (tid < c)
                f = (__hip_atomic_load(&flags[tid], __ATOMIC_ACQUIRE,
                                       __HIP_MEMORY_SCOPE_AGENT) != 0);
            ok = __syncthreads_and(f);
        } while (!ok);
        __threadfence();

        const float2* aggf = (const float2*)agg;
        float fr = 1.f, fi = 0.f;     // A_c^0
        int j = c - 1;
        for (; j >= 7; j -= 8) {      // 8 independent loads per batch
            float2 g[8];
            #pragma unroll
            for (int q = 0; q < 8; ++q)
                g[q] = aggf[(size_t)(j - q) * P_DIM + p];
            #pragma unroll
            for (int q = 0; q < 8; ++q) {
                cr += fr * g[q].x - fi * g[q].y;
                ci += fr * g[q].y + fi * g[q].x;
                float nfr = fr * Ar - fi * Ai;
                float nfi = fr * Ai + fi * Ar;
                fr = nfr; fi = nfi;
            }
        }
        for (; j >= 0; --j) {
            float2 g = aggf[(size_t)j * P_DIM + p];
            cr += fr * g.x - fi * g.y;
            ci += fr * g.y + fi * g.x;
            float nfr = fr * Ar - fi * Ai;
            float nfi = fr * Ai + fi * Ar;
            fr = nfr; fi = nfi;
        }
    }

    // pass B: rescan with carry init, emit packed bf16 (coalesced dwords)
    xr = cr; xi = ci;
    unsigned int* Ap32 = (unsigned int*)(A + (size_t)c * CHUNK * KDIM);
    #pragma unroll
    for (int t = 0; t < CHUNK; ++t) {
        float nr = ar * xr - ai * xi + br * uv[t];
        float ni = ar * xi + ai * xr + bi * uv[t];
        xr = nr; xi = ni;
        union { unsigned int w; bf16_t h[2]; } o;
        o.h[0] = (bf16_t)xr;
        o.h[1] = (bf16_t)xi;
        Ap32[(size_t)t * (KDIM / 2) + p] = o.w;
    }
}

// GEMM: out[m][n] = spike(sum_k A[m][k]*Bt[n][k]).
// 128x256 tile (A refetched only 2x vs 4x at BN=128), BK=64, 256 thr
// (4 waves, each 64x128: af[4] x bfv[8] -> 32 MFMA per K-chunk).
// global_load_lds width-16; global source order XOR-swizzled so lane-linear
// LDS gives 2-way-max ds_read_b128.
__global__ void __launch_bounds__(256, 2) k_gemm(const bf16_t* __restrict__ A,
        const bf16_t* __restrict__ Bt, float* __restrict__ out) {
    __shared__ __align__(16) bf16_t As[BM * BK];   // 16 KB
    __shared__ __align__(16) bf16_t Bs[BN * BK];   // 32 KB

    const int tid  = threadIdx.x;
    const int lane = tid & 63;
    const int w    = tid >> 6;
    const int m0   = blockIdx.x * BM;
    const int n0   = blockIdx.y * BN;
    const int wm   = (w & 1) * 64;
    const int wn   = (w >> 1) * 128;
    const int fr_m = lane & 15;
    const int fr_g = lane >> 4;

    floatx4 acc[4][8];
    #pragma unroll
    for (int i = 0; i < 4; ++i)
        #pragma unroll
        for (int j = 0; j < 8; ++j) {
            floatx4 z = {0.f, 0.f, 0.f, 0.f};
            acc[i][j] = z;
        }

    const bf16_t* Asrc = A  + (size_t)m0 * KDIM;
    const bf16_t* Bsrc = Bt + (size_t)n0 * KDIM;

    for (int kt = 0; kt < KDIM; kt += BK) {
        __syncthreads();
        // A: 1024 16B-chunks
        #pragma unroll
        for (int i = 0; i < 4; ++i) {
            const int cb = i * 256 + w * 64;        // uniform per wave
            const int c  = cb + lane;
            const int r  = c >> 3;
            const int gc = (c & 7) ^ (r & 7);       // swizzled source chunk
            const bf16_t* ga = Asrc + (size_t)r * KDIM + kt + gc * 8;
            __builtin_amdgcn_global_load_lds(
                (const __attribute__((address_space(1))) unsigned int*)ga,
                (__attribute__((address_space(3))) unsigned int*)((char*)As + cb * 16),
                16, 0, 0);
        }
        // B: 2048 16B-chunks
        #pragma unroll
        for (int i = 0; i < 8; ++i) {
            const int cb = i * 256 + w * 64;
            const int c  = cb + lane;
            const int r  = c >> 3;
            const int gc = (c & 7) ^ (r & 7);
            const bf16_t* gb = Bsrc + (size_t)r * KDIM + kt + gc * 8;
            __builtin_amdgcn_global_load_lds(
                (const __attribute__((address_space(1))) unsigned int*)gb,
                (__attribute__((address_space(3))) unsigned int*)((char*)Bs + cb * 16),
                16, 0, 0);
        }
        __syncthreads();

        #pragma unroll
        for (int kk = 0; kk < BK; kk += 32) {
            const int kc = (kk >> 3) + fr_g;
            bf16x8 af[4], bfv[8];
            #pragma unroll
            for (int i = 0; i < 4; ++i) {
                int m = wm + i * 16 + fr_m;
                af[i] = *(const bf16x8*)((const char*)As + m * (BK * 2)
                                         + ((kc ^ (m & 7)) << 4));
            }
            #pragma unroll
            for (int j = 0; j < 8; ++j) {
                int n = wn + j * 16 + fr_m;
                bfv[j] = *(const bf16x8*)((const char*)Bs + n * (BK * 2)
                                          + ((kc ^ (n & 7)) << 4));
            }
            #pragma unroll
            for (int i = 0; i < 4; ++i)
                #pragma unroll
                for (int j = 0; j < 8; ++j)
                    acc[i][j] = __builtin_amdgcn_mfma_f32_16x16x32_bf16(
                        af[i], bfv[j], acc[i][j], 0, 0, 0);
        }
    }

    // Epilogue: C/D layout col=lane&15, row=(lane>>4)*4+reg (m89-verified).
    #pragma unroll
    for (int i = 0; i < 4; ++i)
        #pragma unroll
        for (int j = 0; j < 8; ++j)
            #pragma unroll
            for (int r = 0; r < 4; ++r) {
                int rr = wm + i * 16 + fr_g * 4 + r;
                int cl = wn + j * 16 + fr_m;
                out[(size_t)(m0 + rr) * NDIM + (n0 + cl)] =
                    (acc[i][j][r] > 1.0f) ? 1.0f : 0.0f;
            }
}

extern "C" void kernel_launch(void* const* d_in, const int* in_sizes, int n_in,
                              void* d_out, int out_size, void* d_ws, size_t ws_size,
                              hipStream_t stream) {
    (void)in_sizes; (void)n_in; (void)out_size; (void)ws_size;
    const float* u     = (const float*)d_in[0];
    const float* Lam   = (const float*)d_in[1];
    const float* lstep = (const float*)d_in[2];
    const float* Vre   = (const float*)d_in[3];
    const float* Vim   = (const float*)d_in[4];
    float* out = (float*)d_out;

    char* ws = (char*)d_ws;
    unsigned int*       flags = (unsigned int*)(ws);                  // 1 KB
    unsigned long long* agg   = (unsigned long long*)(ws + 0x100000); // 1 MB
    bf16_t*             Bt    = (bf16_t*)(ws + 0x200000);             // 1 MB
    bf16_t*             A     = (bf16_t*)(ws + 0x400000);             // 32 MB

    hipMemsetAsync(flags, 0, NCHUNK * sizeof(unsigned int), stream);
    hipLaunchKernelGGL(k_scan_fused, dim3(NBT + NCHUNK), dim3(512), 0, stream,
                       u, Lam, lstep, Vre, Vim, flags, agg, Bt, A);
    hipLaunchKernelGGL(k_gemm, dim3(L_LEN / BM, NDIM / BN), dim3(256), 0, stream,
                       A, Bt, out);
}

// Round 6
// 200.988 us; speedup vs baseline: 1.1445x; 1.1445x over previous
//
#include <hip/hip_runtime.h>
#include <hip/hip_cooperative_groups.h>

namespace cg = cooperative_groups;

#define L_LEN   16384
#define P_DIM   512
#define CHUNK   64
#define NCHUNK  256        // L_LEN / CHUNK

#define KDIM    1024       // 2*P, interleaved: k=2c -> re(ch c), k=2c+1 -> im(ch c)
#define NDIM    512
#define BM      128
#define BN      256
#define BK      64

typedef __bf16 bf16_t;
typedef __bf16 bf16x8 __attribute__((ext_vector_type(8)));
typedef float  floatx4 __attribute__((ext_vector_type(4)));

// Cooperative scan: one kernel, grid.sync() instead of round-4/5's
// flag/spin/fence protocol (that protocol itself was the 117-148us cost:
// agent-scope acquire loads are ~900cy and unpipelinable).
// Phase 1: local scan chunk c from zero (u cached in uv[64] regs), write
//          ends[c]; pack this block's 1/256 slice of Bt.
// sync.
// Phase 2: carry_c = sum_{j<c} A^(c-1-j) * ends_j  -- plain pipelined loads
//          (L2-resident 1 MB), backward factor chain (|A|<1, stable).
// Phase 3: rescan with carry init, emit bf16 A row-major k-interleaved.
__global__ void __launch_bounds__(512, 4) k_scan_coop(
        const float* __restrict__ u, const float* __restrict__ Lam,
        const float* __restrict__ lstep, const float* __restrict__ Vre,
        const float* __restrict__ Vim, float2* __restrict__ ends,
        bf16_t* __restrict__ Bt, bf16_t* __restrict__ A) {
    const int c = blockIdx.x;
    const int p = threadIdx.x;

    // per-channel constants
    float lr = -expf(Lam[2 * p + 0]);
    float li = Lam[2 * p + 1];
    float s  = expf(lstep[p]);
    float er = expf(lr * s);
    float ar = er * cosf(li * s);
    float ai = er * sinf(li * s);
    float dr = ar - 1.0f, di = ai;
    float inv = 1.0f / (lr * lr + li * li);
    float br = (dr * lr + di * li) * inv;
    float bi = (di * lr - dr * li) * inv;
    // chunk-combine factor A_c = a^CHUNK (closed form)
    float tt = s * (float)CHUNK;
    float eR = expf(lr * tt);
    float Ar = eR * cosf(li * tt);
    float Ai = eR * sinf(li * tt);

    // ---- phase 1: local scan from zero, cache u in registers ----
    float uv[CHUNK];
    const float* up = u + (size_t)c * CHUNK * P_DIM + p;
    float xr = 0.f, xi = 0.f;
    #pragma unroll
    for (int t = 0; t < CHUNK; ++t) {
        uv[t] = up[(size_t)t * P_DIM];
        float nr = ar * xr - ai * xi + br * uv[t];
        float ni = ar * xi + ai * xr + bi * uv[t];
        xr = nr; xi = ni;
    }
    ends[c * P_DIM + p] = make_float2(xr, xi);

    // Bt pack slice: dwords [c*1024, c*1024+1024)
    {
        const int base = c * 1024;
        #pragma unroll
        for (int i = 0; i < 2; ++i) {
            int idx = base + i * 512 + p;
            int j  = idx >> 9;
            int cc = idx & 511;
            union { unsigned int w; bf16_t h[2]; } pk;
            pk.h[0] = (bf16_t)Vre[j * P_DIM + cc];
            pk.h[1] = (bf16_t)(-Vim[j * P_DIM + cc]);
            ((unsigned int*)Bt)[idx] = pk.w;
        }
    }

    cg::this_grid().sync();

    // ---- phase 2: lookback carry, plain batched loads ----
    float cr = 0.f, ci = 0.f;
    {
        float fr = 1.f, fi = 0.f;     // A_c^0
        int j = c - 1;
        for (; j >= 7; j -= 8) {      // 8 independent loads per batch
            float2 g[8];
            #pragma unroll
            for (int q = 0; q < 8; ++q)
                g[q] = ends[(size_t)(j - q) * P_DIM + p];
            #pragma unroll
            for (int q = 0; q < 8; ++q) {
                cr += fr * g[q].x - fi * g[q].y;
                ci += fr * g[q].y + fi * g[q].x;
                float nfr = fr * Ar - fi * Ai;
                float nfi = fr * Ai + fi * Ar;
                fr = nfr; fi = nfi;
            }
        }
        for (; j >= 0; --j) {
            float2 g = ends[(size_t)j * P_DIM + p];
            cr += fr * g.x - fi * g.y;
            ci += fr * g.y + fi * g.x;
            float nfr = fr * Ar - fi * Ai;
            float nfi = fr * Ai + fi * Ar;
            fr = nfr; fi = nfi;
        }
    }

    // ---- phase 3: rescan with carry init, emit packed bf16 ----
    xr = cr; xi = ci;
    unsigned int* Ap32 = (unsigned int*)(A + (size_t)c * CHUNK * KDIM);
    #pragma unroll
    for (int t = 0; t < CHUNK; ++t) {
        float nr = ar * xr - ai * xi + br * uv[t];
        float ni = ar * xi + ai * xr + bi * uv[t];
        xr = nr; xi = ni;
        union { unsigned int w; bf16_t h[2]; } o;
        o.h[0] = (bf16_t)xr;
        o.h[1] = (bf16_t)xi;
        Ap32[(size_t)t * (KDIM / 2) + p] = o.w;
    }
}

// GEMM: out[m][n] = spike(sum_k A[m][k]*Bt[n][k]).
// 128x256 tile, BK=64, 256 thr (4 waves, each 64x128: af[4] x bfv[8]).
// global_load_lds width-16; global source order XOR-swizzled so lane-linear
// LDS gives 2-way-max ds_read_b128.
__global__ void __launch_bounds__(256, 2) k_gemm(const bf16_t* __restrict__ A,
        const bf16_t* __restrict__ Bt, float* __restrict__ out) {
    __shared__ __align__(16) bf16_t As[BM * BK];   // 16 KB
    __shared__ __align__(16) bf16_t Bs[BN * BK];   // 32 KB

    const int tid  = threadIdx.x;
    const int lane = tid & 63;
    const int w    = tid >> 6;
    const int m0   = blockIdx.x * BM;
    const int n0   = blockIdx.y * BN;
    const int wm   = (w & 1) * 64;
    const int wn   = (w >> 1) * 128;
    const int fr_m = lane & 15;
    const int fr_g = lane >> 4;

    floatx4 acc[4][8];
    #pragma unroll
    for (int i = 0; i < 4; ++i)
        #pragma unroll
        for (int j = 0; j < 8; ++j) {
            floatx4 z = {0.f, 0.f, 0.f, 0.f};
            acc[i][j] = z;
        }

    const bf16_t* Asrc = A  + (size_t)m0 * KDIM;
    const bf16_t* Bsrc = Bt + (size_t)n0 * KDIM;

    for (int kt = 0; kt < KDIM; kt += BK) {
        __syncthreads();
        #pragma unroll
        for (int i = 0; i < 4; ++i) {
            const int cb = i * 256 + w * 64;        // uniform per wave
            const int cc = cb + lane;
            const int r  = cc >> 3;
            const int gc = (cc & 7) ^ (r & 7);      // swizzled source chunk
            const bf16_t* ga = Asrc + (size_t)r * KDIM + kt + gc * 8;
            __builtin_amdgcn_global_load_lds(
                (const __attribute__((address_space(1))) unsigned int*)ga,
                (__attribute__((address_space(3))) unsigned int*)((char*)As + cb * 16),
                16, 0, 0);
        }
        #pragma unroll
        for (int i = 0; i < 8; ++i) {
            const int cb = i * 256 + w * 64;
            const int cc = cb + lane;
            const int r  = cc >> 3;
            const int gc = (cc & 7) ^ (r & 7);
            const bf16_t* gb = Bsrc + (size_t)r * KDIM + kt + gc * 8;
            __builtin_amdgcn_global_load_lds(
                (const __attribute__((address_space(1))) unsigned int*)gb,
                (__attribute__((address_space(3))) unsigned int*)((char*)Bs + cb * 16),
                16, 0, 0);
        }
        __syncthreads();

        #pragma unroll
        for (int kk = 0; kk < BK; kk += 32) {
            const int kc = (kk >> 3) + fr_g;
            bf16x8 af[4], bfv[8];
            #pragma unroll
            for (int i = 0; i < 4; ++i) {
                int m = wm + i * 16 + fr_m;
                af[i] = *(const bf16x8*)((const char*)As + m * (BK * 2)
                                         + ((kc ^ (m & 7)) << 4));
            }
            #pragma unroll
            for (int j = 0; j < 8; ++j) {
                int n = wn + j * 16 + fr_m;
                bfv[j] = *(const bf16x8*)((const char*)Bs + n * (BK * 2)
                                          + ((kc ^ (n & 7)) << 4));
            }
            #pragma unroll
            for (int i = 0; i < 4; ++i)
                #pragma unroll
                for (int j = 0; j < 8; ++j)
                    acc[i][j] = __builtin_amdgcn_mfma_f32_16x16x32_bf16(
                        af[i], bfv[j], acc[i][j], 0, 0, 0);
        }
    }

    // Epilogue: C/D layout col=lane&15, row=(lane>>4)*4+reg (m89-verified).
    #pragma unroll
    for (int i = 0; i < 4; ++i)
        #pragma unroll
        for (int j = 0; j < 8; ++j)
            #pragma unroll
            for (int r = 0; r < 4; ++r) {
                int rr = wm + i * 16 + fr_g * 4 + r;
                int cl = wn + j * 16 + fr_m;
                out[(size_t)(m0 + rr) * NDIM + (n0 + cl)] =
                    (acc[i][j][r] > 1.0f) ? 1.0f : 0.0f;
            }
}

extern "C" void kernel_launch(void* const* d_in, const int* in_sizes, int n_in,
                              void* d_out, int out_size, void* d_ws, size_t ws_size,
                              hipStream_t stream) {
    (void)in_sizes; (void)n_in; (void)out_size; (void)ws_size;
    const float* u     = (const float*)d_in[0];
    const float* Lam   = (const float*)d_in[1];
    const float* lstep = (const float*)d_in[2];
    const float* Vre   = (const float*)d_in[3];
    const float* Vim   = (const float*)d_in[4];
    float* out = (float*)d_out;

    char* ws = (char*)d_ws;
    float2* ends = (float2*)(ws);                         // 1 MB
    bf16_t* Bt   = (bf16_t*)(ws + 0x100000);              // 1 MB
    bf16_t* A    = (bf16_t*)(ws + 0x400000);              // 32 MB

    void* args[] = {(void*)&u, (void*)&Lam, (void*)&lstep, (void*)&Vre,
                    (void*)&Vim, (void*)&ends, (void*)&Bt, (void*)&A};
    hipLaunchCooperativeKernel((void*)k_scan_coop, dim3(NCHUNK), dim3(512),
                               args, 0, stream);
    hipLaunchKernelGGL(k_gemm, dim3(L_LEN / BM, NDIM / BN), dim3(256), 0, stream,
                       A, Bt, out);
}